// Round 7
// baseline (1181.220 us; speedup 1.0000x reference)
//
#include <hip/hip_runtime.h>

typedef _Float16 half8 __attribute__((ext_vector_type(8)));
typedef __attribute__((ext_vector_type(4))) float f32x4;

__device__ __forceinline__ unsigned short f2h(float f) {
    _Float16 h = (_Float16)f;
    return *(unsigned short*)&h;
}
__device__ __forceinline__ float h2f(unsigned short u) {
    _Float16 h = *(_Float16*)&u;
    return (float)h;
}

// ---------- preprocessing: counting sort by key = dst*8 + rel ----------

__global__ __launch_bounds__(256) void hist8_kernel(
    const int* __restrict__ dst, const int* __restrict__ et,
    int* __restrict__ hist, int E)
{
    int e = blockIdx.x * 256 + threadIdx.x;
    if (e < E) atomicAdd(&hist[dst[e] * 8 + et[e]], 1);
}

#define SCAN_TILE 4096
__global__ __launch_bounds__(1024) void scanA_kernel(
    const int* __restrict__ hist, int* __restrict__ bstart,
    int* __restrict__ partial, int nkeys)
{
    __shared__ int wsum[16];
    const int t = threadIdx.x;
    const int lane = t & 63, w = t >> 6;
    const int base = blockIdx.x * SCAN_TILE + t * 4;
    int v[4];
    int s = 0;
#pragma unroll
    for (int i = 0; i < 4; ++i) {
        v[i] = (base + i < nkeys) ? hist[base + i] : 0;
        s += v[i];
    }
    int inc = s;
#pragma unroll
    for (int off = 1; off < 64; off <<= 1) {
        int u = __shfl_up(inc, off);
        if (lane >= off) inc += u;
    }
    if (lane == 63) wsum[w] = inc;
    __syncthreads();
    if (w == 0 && lane < 16) {
        int ws = wsum[lane];
        int winc = ws;
#pragma unroll
        for (int off = 1; off < 16; off <<= 1) {
            int u = __shfl_up(winc, off);
            if (lane >= off) winc += u;
        }
        wsum[lane] = winc - ws;   // exclusive
    }
    __syncthreads();
    int run = wsum[w] + (inc - s);
    int tbase = run;
#pragma unroll
    for (int i = 0; i < 4; ++i) {
        if (base + i < nkeys) bstart[base + i] = run;
        run += v[i];
    }
    if (t == 1023) partial[blockIdx.x] = tbase + s;   // block total
}

__global__ __launch_bounds__(64) void scanB_kernel(
    const int* __restrict__ partial, int* __restrict__ pscan,
    int* __restrict__ bstart_end, int nblk)
{
    const int lane = threadIdx.x;
    int running = 0;
    for (int b = 0; b < nblk; b += 64) {
        int i = b + lane;
        int o = (i < nblk) ? partial[i] : 0;
        int v = o;
#pragma unroll
        for (int off = 1; off < 64; off <<= 1) {
            int u = __shfl_up(v, off);
            if (lane >= off) v += u;
        }
        if (i < nblk) pscan[i] = running + v - o;
        running += __shfl(v, 63);
    }
    if (lane == 0) *bstart_end = running;   // == E
}

__global__ __launch_bounds__(1024) void scanC_kernel(
    int* __restrict__ bstart, const int* __restrict__ pscan, int nkeys)
{
    int i = blockIdx.x * 1024 + threadIdx.x;
    if (i < nkeys) bstart[i] += pscan[i / SCAN_TILE];
}

__global__ __launch_bounds__(256) void scatter8_kernel(
    const int* __restrict__ src, const int* __restrict__ dst,
    const int* __restrict__ et, const int* __restrict__ bstart,
    int* __restrict__ cursor, unsigned* __restrict__ srt, int E)
{
    int e = blockIdx.x * 256 + threadIdx.x;
    if (e < E) {
        int key = dst[e] * 8 + et[e];
        int pos = bstart[key] + atomicAdd(&cursor[key], 1);
        srt[pos] = (unsigned)src[e] | ((unsigned)et[e] << 17);
    }
}

// ---------- x -> compact f16 ----------
__global__ __launch_bounds__(256) void xprep_kernel(
    const float* __restrict__ x, unsigned short* __restrict__ xh, int n)
{
    int i = blockIdx.x * 256 + threadIdx.x;
    if (i < n) xh[i] = f2h(x[i]);
}

// ---------- W preconversion: f16 image, chunk c: [j][k stride 72] ----------

__global__ __launch_bounds__(256) void wprep_kernel(
    const float* __restrict__ W, const float* __restrict__ root,
    unsigned short* __restrict__ wb, int dout)
{
    int idx = blockIdx.x * 256 + threadIdx.x;
    int total = 9 * 64 * dout;
    if (idx >= total) return;
    int c = idx / (64 * dout);
    int rme = idx % (64 * dout);
    int kk = rme / dout;
    int j = rme % dout;
    float f = (c == 0) ? root[kk * dout + j]
                       : W[(size_t)(c - 1) * 64 * dout + kk * dout + j];
    wb[(size_t)c * dout * 72 + (size_t)j * 72 + kk] = f2h(f);
}

// ---------- aggregation: one wave per node, lane = feature dim ----------
// Per-wave LDS acc[8 rel][64 lane]; per edge: shfl rec -> gather f16 -> ds_add.
// Writes A[n] = [ feat[n] | mean_0 .. mean_7 ] (f16, 576 cols).

__global__ __launch_bounds__(512) void agg_kernel(
    const unsigned short* __restrict__ feat,  // (N, 64) f16 compact
    const unsigned* __restrict__ srt,         // sorted (src | rel<<17)
    const int* __restrict__ bstart,           // (N*8 + 1)
    unsigned short* __restrict__ A,           // (N, 576) f16
    int n_nodes)
{
    __shared__ float acc_s[8][8][64];   // [wave][rel][lane], 16 KB
    const int t = threadIdx.x;
    const int lane = t & 63;
    const int w = t >> 6;
    float* wacc = &acc_s[w][0][0];
#pragma unroll
    for (int r = 0; r < 8; ++r) wacc[r * 64 + lane] = 0.0f;  // wave-private

    const int node = blockIdx.x * 8 + w;
    if (node >= n_nodes) return;
    int myb = 0;
    if (lane < 9) myb = bstart[node * 8 + lane];
    const int e0 = __shfl(myb, 0);
    const int e1 = __shfl(myb, 8);

#define GATHER(q) h2f(feat[(size_t)((q) & 0x1FFFF) * 64 + lane])
#define DSADD(q, v) atomicAdd(&wacc[(((q) >> 17) & 7) * 64 + lane], (v))

    for (int base = e0; base < e1; base += 64) {
        const int blen = min(64, e1 - base);
        unsigned rec = (lane < blen) ? srt[base + lane] : 0u;
        int k = 0;
        for (; k + 4 <= blen; k += 4) {
            unsigned q0 = __shfl(rec, k), q1 = __shfl(rec, k + 1);
            unsigned q2 = __shfl(rec, k + 2), q3 = __shfl(rec, k + 3);
            float v0 = GATHER(q0), v1 = GATHER(q1);
            float v2 = GATHER(q2), v3 = GATHER(q3);
            DSADD(q0, v0); DSADD(q1, v1); DSADD(q2, v2); DSADD(q3, v3);
        }
        for (; k < blen; ++k) {
            unsigned q = __shfl(rec, k);
            float v = GATHER(q);
            DSADD(q, v);
        }
    }
#undef GATHER
#undef DSADD

    unsigned short* arow = A + (size_t)node * 576;
    arow[lane] = feat[(size_t)node * 64 + lane];   // self features (cols 0:63)
#pragma unroll
    for (int r = 0; r < 8; ++r) {
        int c0 = __shfl(myb, r);
        int c1 = __shfl(myb, r + 1);
        float m = wacc[r * 64 + lane] / fmaxf((float)(c1 - c0), 1.0f);
        arow[64 + r * 64 + lane] = f2h(m);
    }
}

// ---------- dense: C = A @ [root; W] + b, f16 MFMA, whole W in LDS ----------
// Block = 128 nodes, 512 threads = 8 waves (wave = one 16-row m-tile, all j).

template <int DOUT, int RELU, int OUTH>
__global__ __launch_bounds__(512, 2) void dense_kernel(
    const unsigned short* __restrict__ A,   // (N, 576) f16
    const unsigned short* __restrict__ wb,  // (9, DOUT, 72) f16
    const float* __restrict__ bias,
    float* __restrict__ outf,               // fp32 out (OUTH=0)
    unsigned short* __restrict__ outh,      // f16 out, compact (N,64) (OUTH=1)
    int n_nodes)
{
    constexpr int WSHORTS = 9 * DOUT * 72;
    __shared__ __align__(16) unsigned short wt_s[WSHORTS];

    const int t = threadIdx.x;
    const int w = t >> 6, lane = t & 63;
    const int quad = lane >> 4, l16 = lane & 15;
    const int node0 = blockIdx.x * 128;
    const int m = w * 16 + l16;
    const int row = min(node0 + m, n_nodes - 1);
    const unsigned short* arow = A + (size_t)row * 576;

    half8 a[18];
#pragma unroll
    for (int c = 0; c < 9; ++c) {
        a[2 * c]     = *(const half8*)(arow + c * 64 + quad * 8);
        a[2 * c + 1] = *(const half8*)(arow + c * 64 + 32 + quad * 8);
    }
    {
        uint4* d4 = (uint4*)wt_s;
        const uint4* s4 = (const uint4*)wb;
        for (int i = t; i < WSHORTS / 8; i += 512) d4[i] = s4[i];
    }
    __syncthreads();

    constexpr int JPW = DOUT / 16;
    f32x4 d[JPW];
#pragma unroll
    for (int i = 0; i < JPW; ++i) d[i] = {0.f, 0.f, 0.f, 0.f};

#pragma unroll
    for (int c = 0; c < 9; ++c) {
#pragma unroll
        for (int jj = 0; jj < JPW; ++jj) {
            const int j = jj * 16 + l16;
            half8 b0 = *(const half8*)&wt_s[c * DOUT * 72 + j * 72 + quad * 8];
            half8 b1 = *(const half8*)&wt_s[c * DOUT * 72 + j * 72 + 32 + quad * 8];
            d[jj] = __builtin_amdgcn_mfma_f32_16x16x32_f16(a[2 * c], b0, d[jj], 0, 0, 0);
            d[jj] = __builtin_amdgcn_mfma_f32_16x16x32_f16(a[2 * c + 1], b1, d[jj], 0, 0, 0);
        }
    }

    // epilogue: C/D layout col = lane&15 (j), row = quad*4 + reg (m)
#pragma unroll
    for (int jj = 0; jj < JPW; ++jj) {
        const int j = jj * 16 + l16;
        const float bj = bias[j];
#pragma unroll
        for (int r = 0; r < 4; ++r) {
            const int node = node0 + w * 16 + quad * 4 + r;
            if (node < n_nodes) {
                float v = d[jj][r] + bj;
                if (RELU) v = fmaxf(v, 0.0f);
                if (OUTH) outh[(size_t)node * 64 + j] = f2h(v);
                else      outf[(size_t)node * DOUT + j] = v;
            }
        }
    }
}

extern "C" void kernel_launch(void* const* d_in, const int* in_sizes, int n_in,
                              void* d_out, int out_size, void* d_ws, size_t ws_size,
                              hipStream_t stream) {
    const float* x     = (const float*)d_in[0];
    const float* W1    = (const float*)d_in[1];
    const float* root1 = (const float*)d_in[2];
    const float* b1    = (const float*)d_in[3];
    const float* W2    = (const float*)d_in[4];
    const float* root2 = (const float*)d_in[5];
    const float* b2    = (const float*)d_in[6];
    const int*   src   = (const int*)d_in[7];
    const int*   dst   = (const int*)d_in[8];
    const int*   et    = (const int*)d_in[9];

    const int N = in_sizes[0] / 64;
    const int E = in_sizes[7];
    const int KEYS = N * 8;

    char* p = (char*)d_ws;
    auto alloc = [&](size_t bytes) {
        char* r = p;
        p += (bytes + 15) & ~(size_t)15;
        return r;
    };
    unsigned* srt       = (unsigned*)alloc((size_t)E * 4);
    int* hist           = (int*)alloc((size_t)KEYS * 4);   // hist|cursor adjacent
    int* cursor         = (int*)alloc((size_t)KEYS * 4);
    int* bstart         = (int*)alloc((size_t)(KEYS + 1) * 4);
    int* partial        = (int*)alloc(256 * 4);
    int* pscan          = (int*)alloc(256 * 4);
    unsigned short* wb1 = (unsigned short*)alloc((size_t)9 * 64 * 72 * 2);
    unsigned short* wb2 = (unsigned short*)alloc((size_t)9 * 32 * 72 * 2);
    unsigned short* xh  = (unsigned short*)alloc((size_t)N * 64 * 2);
    unsigned short* hC  = (unsigned short*)alloc((size_t)N * 64 * 2);
    unsigned short* A   = (unsigned short*)alloc((size_t)N * 576 * 2);
    (void)cursor;  // memset covers hist+cursor together (contiguous)

    hipMemsetAsync(hist, 0, (size_t)KEYS * 8, stream);
    wprep_kernel<<<(9 * 64 * 64 + 255) / 256, 256, 0, stream>>>(W1, root1, wb1, 64);
    wprep_kernel<<<(9 * 64 * 32 + 255) / 256, 256, 0, stream>>>(W2, root2, wb2, 32);
    xprep_kernel<<<(N * 64 + 255) / 256, 256, 0, stream>>>(x, xh, N * 64);
    hist8_kernel<<<(E + 255) / 256, 256, 0, stream>>>(dst, et, hist, E);
    const int nscan = (KEYS + SCAN_TILE - 1) / SCAN_TILE;
    scanA_kernel<<<nscan, 1024, 0, stream>>>(hist, bstart, partial, KEYS);
    scanB_kernel<<<1, 64, 0, stream>>>(partial, pscan, bstart + KEYS, nscan);
    scanC_kernel<<<(KEYS + 1023) / 1024, 1024, 0, stream>>>(bstart, pscan, KEYS);
    scatter8_kernel<<<(E + 255) / 256, 256, 0, stream>>>(src, dst, et, bstart, cursor, srt, E);

    agg_kernel<<<(N + 7) / 8, 512, 0, stream>>>(xh, srt, bstart, A, N);
    dense_kernel<64, 1, 1><<<(N + 127) / 128, 512, 0, stream>>>(
        A, wb1, b1, nullptr, hC, N);
    agg_kernel<<<(N + 7) / 8, 512, 0, stream>>>(hC, srt, bstart, A, N);
    dense_kernel<32, 0, 0><<<(N + 127) / 128, 512, 0, stream>>>(
        A, wb2, b2, (float*)d_out, nullptr, N);
}

// Round 8
// 543.804 us; speedup vs baseline: 2.1721x; 2.1721x over previous
//
#include <hip/hip_runtime.h>

typedef _Float16 half8 __attribute__((ext_vector_type(8)));
typedef __attribute__((ext_vector_type(4))) float f32x4;

__device__ __forceinline__ unsigned short f2h(float f) {
    _Float16 h = (_Float16)f;
    return *(unsigned short*)&h;
}
__device__ __forceinline__ float h2f(unsigned short u) {
    _Float16 h = *(_Float16*)&u;
    return (float)h;
}

// ---------- preprocessing: counting sort by key = dst*8 + rel ----------

__global__ __launch_bounds__(256) void hist8_kernel(
    const int* __restrict__ dst, const int* __restrict__ et,
    int* __restrict__ hist, int E)
{
    int e = blockIdx.x * 256 + threadIdx.x;
    if (e < E) atomicAdd(&hist[dst[e] * 8 + et[e]], 1);
}

#define SCAN_TILE 4096
__global__ __launch_bounds__(1024) void scanA_kernel(
    const int* __restrict__ hist, int* __restrict__ bstart,
    int* __restrict__ partial, int nkeys)
{
    __shared__ int wsum[16];
    const int t = threadIdx.x;
    const int lane = t & 63, w = t >> 6;
    const int base = blockIdx.x * SCAN_TILE + t * 4;
    int v[4];
    int s = 0;
#pragma unroll
    for (int i = 0; i < 4; ++i) {
        v[i] = (base + i < nkeys) ? hist[base + i] : 0;
        s += v[i];
    }
    int inc = s;
#pragma unroll
    for (int off = 1; off < 64; off <<= 1) {
        int u = __shfl_up(inc, off);
        if (lane >= off) inc += u;
    }
    if (lane == 63) wsum[w] = inc;
    __syncthreads();
    if (w == 0 && lane < 16) {
        int ws = wsum[lane];
        int winc = ws;
#pragma unroll
        for (int off = 1; off < 16; off <<= 1) {
            int u = __shfl_up(winc, off);
            if (lane >= off) winc += u;
        }
        wsum[lane] = winc - ws;   // exclusive
    }
    __syncthreads();
    int run = wsum[w] + (inc - s);
    int tbase = run;
#pragma unroll
    for (int i = 0; i < 4; ++i) {
        if (base + i < nkeys) bstart[base + i] = run;
        run += v[i];
    }
    if (t == 1023) partial[blockIdx.x] = tbase + s;   // block total
}

__global__ __launch_bounds__(64) void scanB_kernel(
    const int* __restrict__ partial, int* __restrict__ pscan,
    int* __restrict__ bstart_end, int nblk)
{
    const int lane = threadIdx.x;
    int running = 0;
    for (int b = 0; b < nblk; b += 64) {
        int i = b + lane;
        int o = (i < nblk) ? partial[i] : 0;
        int v = o;
#pragma unroll
        for (int off = 1; off < 64; off <<= 1) {
            int u = __shfl_up(v, off);
            if (lane >= off) v += u;
        }
        if (i < nblk) pscan[i] = running + v - o;
        running += __shfl(v, 63);
    }
    if (lane == 0) *bstart_end = running;   // == E
}

__global__ __launch_bounds__(1024) void scanC_kernel(
    int* __restrict__ bstart, const int* __restrict__ pscan, int nkeys)
{
    int i = blockIdx.x * 1024 + threadIdx.x;
    if (i < nkeys) bstart[i] += pscan[i / SCAN_TILE];
}

__global__ __launch_bounds__(256) void scatter8_kernel(
    const int* __restrict__ src, const int* __restrict__ dst,
    const int* __restrict__ et, const int* __restrict__ bstart,
    int* __restrict__ cursor, unsigned* __restrict__ srt, int E)
{
    int e = blockIdx.x * 256 + threadIdx.x;
    if (e < E) {
        int key = dst[e] * 8 + et[e];
        int pos = bstart[key] + atomicAdd(&cursor[key], 1);
        srt[pos] = (unsigned)src[e] | ((unsigned)et[e] << 17);
    }
}

// ---------- x -> compact f16 ----------
__global__ __launch_bounds__(256) void xprep_kernel(
    const float* __restrict__ x, unsigned short* __restrict__ xh, int n)
{
    int i = blockIdx.x * 256 + threadIdx.x;
    if (i < n) xh[i] = f2h(x[i]);
}

// ---------- W preconversion: f16 image, chunk c: [j][k stride 72] ----------

__global__ __launch_bounds__(256) void wprep_kernel(
    const float* __restrict__ W, const float* __restrict__ root,
    unsigned short* __restrict__ wb, int dout)
{
    int idx = blockIdx.x * 256 + threadIdx.x;
    int total = 9 * 64 * dout;
    if (idx >= total) return;
    int c = idx / (64 * dout);
    int rme = idx % (64 * dout);
    int kk = rme / dout;
    int j = rme % dout;
    float f = (c == 0) ? root[kk * dout + j]
                       : W[(size_t)(c - 1) * 64 * dout + kk * dout + j];
    wb[(size_t)c * dout * 72 + (size_t)j * 72 + kk] = f2h(f);
}

// ---------- aggregation: one wave per node, lane = feature dim ----------
// Register accumulators; per-relation segment loops (edges are rel-sorted,
// boundaries from bstart) -> no per-edge relation select, no LDS.
// Writes A[n] = [ feat[n] | mean_0 .. mean_7 ] (f16, 576 cols).

__global__ __launch_bounds__(512) void agg_kernel(
    const unsigned short* __restrict__ feat,  // (N, 64) f16 compact
    const unsigned* __restrict__ srt,         // sorted (src | rel<<17)
    const int* __restrict__ bstart,           // (N*8 + 1)
    unsigned short* __restrict__ A,           // (N, 576) f16
    int n_nodes)
{
    const int t = threadIdx.x;
    const int lane = t & 63;
    const int node = blockIdx.x * 8 + (t >> 6);
    if (node >= n_nodes) return;
    int myb = 0;
    if (lane < 9) myb = bstart[node * 8 + lane];
    int cb[9];
#pragma unroll
    for (int r = 0; r < 9; ++r) cb[r] = __shfl(myb, r);
    const int e0 = cb[0];
    const int e1 = cb[8];

    float acc[8];
#pragma unroll
    for (int r = 0; r < 8; ++r) acc[r] = 0.0f;

#define GATHER(q) h2f(feat[(size_t)(q) * 64 + lane])

    for (int base = e0; base < e1; base += 64) {
        const int blen = min(64, e1 - base);
        unsigned rec = (lane < blen) ? srt[base + lane] : 0u;
#pragma unroll
        for (int r = 0; r < 8; ++r) {
            const int s0 = max(cb[r], base) - base;
            const int s1 = min(cb[r + 1], base + blen) - base;
            int k = s0;
            float p0 = 0.f, p1 = 0.f, p2 = 0.f, p3 = 0.f;
            for (; k + 4 <= s1; k += 4) {
                unsigned q0 = __shfl(rec, k) & 0x1FFFF;
                unsigned q1 = __shfl(rec, k + 1) & 0x1FFFF;
                unsigned q2 = __shfl(rec, k + 2) & 0x1FFFF;
                unsigned q3 = __shfl(rec, k + 3) & 0x1FFFF;
                p0 += GATHER(q0);
                p1 += GATHER(q1);
                p2 += GATHER(q2);
                p3 += GATHER(q3);
            }
            for (; k < s1; ++k) {
                unsigned q = __shfl(rec, k) & 0x1FFFF;
                p0 += GATHER(q);
            }
            acc[r] += (p0 + p1) + (p2 + p3);
        }
    }
#undef GATHER

    unsigned short* arow = A + (size_t)node * 576;
    arow[lane] = feat[(size_t)node * 64 + lane];   // self features (cols 0:63)
#pragma unroll
    for (int r = 0; r < 8; ++r) {
        float m = acc[r] / fmaxf((float)(cb[r + 1] - cb[r]), 1.0f);
        arow[64 + r * 64 + lane] = f2h(m);
    }
}

// ---------- dense: C = A @ [root; W] + b, f16 MFMA, whole W in LDS ----------
// Block = 128 nodes, 512 threads = 8 waves (wave = one 16-row m-tile, all j).

template <int DOUT, int RELU, int OUTH>
__global__ __launch_bounds__(512, 2) void dense_kernel(
    const unsigned short* __restrict__ A,   // (N, 576) f16
    const unsigned short* __restrict__ wb,  // (9, DOUT, 72) f16
    const float* __restrict__ bias,
    float* __restrict__ outf,               // fp32 out (OUTH=0)
    unsigned short* __restrict__ outh,      // f16 out, compact (N,64) (OUTH=1)
    int n_nodes)
{
    constexpr int WSHORTS = 9 * DOUT * 72;
    __shared__ __align__(16) unsigned short wt_s[WSHORTS];

    const int t = threadIdx.x;
    const int w = t >> 6, lane = t & 63;
    const int quad = lane >> 4, l16 = lane & 15;
    const int node0 = blockIdx.x * 128;
    const int m = w * 16 + l16;
    const int row = min(node0 + m, n_nodes - 1);
    const unsigned short* arow = A + (size_t)row * 576;

    half8 a[18];
#pragma unroll
    for (int c = 0; c < 9; ++c) {
        a[2 * c]     = *(const half8*)(arow + c * 64 + quad * 8);
        a[2 * c + 1] = *(const half8*)(arow + c * 64 + 32 + quad * 8);
    }
    {
        uint4* d4 = (uint4*)wt_s;
        const uint4* s4 = (const uint4*)wb;
        for (int i = t; i < WSHORTS / 8; i += 512) d4[i] = s4[i];
    }
    __syncthreads();

    constexpr int JPW = DOUT / 16;
    f32x4 d[JPW];
#pragma unroll
    for (int i = 0; i < JPW; ++i) d[i] = {0.f, 0.f, 0.f, 0.f};

#pragma unroll
    for (int c = 0; c < 9; ++c) {
#pragma unroll
        for (int jj = 0; jj < JPW; ++jj) {
            const int j = jj * 16 + l16;
            half8 b0 = *(const half8*)&wt_s[c * DOUT * 72 + j * 72 + quad * 8];
            half8 b1 = *(const half8*)&wt_s[c * DOUT * 72 + j * 72 + 32 + quad * 8];
            d[jj] = __builtin_amdgcn_mfma_f32_16x16x32_f16(a[2 * c], b0, d[jj], 0, 0, 0);
            d[jj] = __builtin_amdgcn_mfma_f32_16x16x32_f16(a[2 * c + 1], b1, d[jj], 0, 0, 0);
        }
    }

    // epilogue: C/D layout col = lane&15 (j), row = quad*4 + reg (m)
#pragma unroll
    for (int jj = 0; jj < JPW; ++jj) {
        const int j = jj * 16 + l16;
        const float bj = bias[j];
#pragma unroll
        for (int r = 0; r < 4; ++r) {
            const int node = node0 + w * 16 + quad * 4 + r;
            if (node < n_nodes) {
                float v = d[jj][r] + bj;
                if (RELU) v = fmaxf(v, 0.0f);
                if (OUTH) outh[(size_t)node * 64 + j] = f2h(v);
                else      outf[(size_t)node * DOUT + j] = v;
            }
        }
    }
}

extern "C" void kernel_launch(void* const* d_in, const int* in_sizes, int n_in,
                              void* d_out, int out_size, void* d_ws, size_t ws_size,
                              hipStream_t stream) {
    const float* x     = (const float*)d_in[0];
    const float* W1    = (const float*)d_in[1];
    const float* root1 = (const float*)d_in[2];
    const float* b1    = (const float*)d_in[3];
    const float* W2    = (const float*)d_in[4];
    const float* root2 = (const float*)d_in[5];
    const float* b2    = (const float*)d_in[6];
    const int*   src   = (const int*)d_in[7];
    const int*   dst   = (const int*)d_in[8];
    const int*   et    = (const int*)d_in[9];

    const int N = in_sizes[0] / 64;
    const int E = in_sizes[7];
    const int KEYS = N * 8;

    char* p = (char*)d_ws;
    auto alloc = [&](size_t bytes) {
        char* r = p;
        p += (bytes + 15) & ~(size_t)15;
        return r;
    };
    unsigned* srt       = (unsigned*)alloc((size_t)E * 4);
    int* hist           = (int*)alloc((size_t)KEYS * 4);   // hist|cursor adjacent
    int* cursor         = (int*)alloc((size_t)KEYS * 4);
    int* bstart         = (int*)alloc((size_t)(KEYS + 1) * 4);
    int* partial        = (int*)alloc(256 * 4);
    int* pscan          = (int*)alloc(256 * 4);
    unsigned short* wb1 = (unsigned short*)alloc((size_t)9 * 64 * 72 * 2);
    unsigned short* wb2 = (unsigned short*)alloc((size_t)9 * 32 * 72 * 2);
    unsigned short* xh  = (unsigned short*)alloc((size_t)N * 64 * 2);
    unsigned short* hC  = (unsigned short*)alloc((size_t)N * 64 * 2);
    unsigned short* A   = (unsigned short*)alloc((size_t)N * 576 * 2);
    (void)cursor;  // memset covers hist+cursor together (contiguous)

    hipMemsetAsync(hist, 0, (size_t)KEYS * 8, stream);
    wprep_kernel<<<(9 * 64 * 64 + 255) / 256, 256, 0, stream>>>(W1, root1, wb1, 64);
    wprep_kernel<<<(9 * 64 * 32 + 255) / 256, 256, 0, stream>>>(W2, root2, wb2, 32);
    xprep_kernel<<<(N * 64 + 255) / 256, 256, 0, stream>>>(x, xh, N * 64);
    hist8_kernel<<<(E + 255) / 256, 256, 0, stream>>>(dst, et, hist, E);
    const int nscan = (KEYS + SCAN_TILE - 1) / SCAN_TILE;
    scanA_kernel<<<nscan, 1024, 0, stream>>>(hist, bstart, partial, KEYS);
    scanB_kernel<<<1, 64, 0, stream>>>(partial, pscan, bstart + KEYS, nscan);
    scanC_kernel<<<(KEYS + 1023) / 1024, 1024, 0, stream>>>(bstart, pscan, KEYS);
    scatter8_kernel<<<(E + 255) / 256, 256, 0, stream>>>(src, dst, et, bstart, cursor, srt, E);

    agg_kernel<<<(N + 7) / 8, 512, 0, stream>>>(xh, srt, bstart, A, N);
    dense_kernel<64, 1, 1><<<(N + 127) / 128, 512, 0, stream>>>(
        A, wb1, b1, nullptr, hC, N);
    agg_kernel<<<(N + 7) / 8, 512, 0, stream>>>(hC, srt, bstart, A, N);
    dense_kernel<32, 0, 0><<<(N + 127) / 128, 512, 0, stream>>>(
        A, wb2, b2, (float*)d_out, nullptr, N);
}

// Round 11
// 531.523 us; speedup vs baseline: 2.2223x; 1.0231x over previous
//
#include <hip/hip_runtime.h>

typedef _Float16 half8 __attribute__((ext_vector_type(8)));
typedef __attribute__((ext_vector_type(4))) float f32x4;

__device__ __forceinline__ unsigned short f2h(float f) {
    _Float16 h = (_Float16)f;
    return *(unsigned short*)&h;
}
__device__ __forceinline__ float h2f(unsigned short u) {
    _Float16 h = *(_Float16*)&u;
    return (float)h;
}

// ---------- preprocessing: counting sort by key = dst*8 + rel ----------

__global__ __launch_bounds__(256) void hist8_kernel(
    const int* __restrict__ dst, const int* __restrict__ et,
    int* __restrict__ hist, int E)
{
    int e = blockIdx.x * 256 + threadIdx.x;
    if (e < E) atomicAdd(&hist[dst[e] * 8 + et[e]], 1);
}

#define SCAN_TILE 4096
__global__ __launch_bounds__(1024) void scanA_kernel(
    const int* __restrict__ hist, int* __restrict__ bstart,
    int* __restrict__ partial, int nkeys)
{
    __shared__ int wsum[16];
    const int t = threadIdx.x;
    const int lane = t & 63, w = t >> 6;
    const int base = blockIdx.x * SCAN_TILE + t * 4;
    int v[4];
    int s = 0;
#pragma unroll
    for (int i = 0; i < 4; ++i) {
        v[i] = (base + i < nkeys) ? hist[base + i] : 0;
        s += v[i];
    }
    int inc = s;
#pragma unroll
    for (int off = 1; off < 64; off <<= 1) {
        int u = __shfl_up(inc, off);
        if (lane >= off) inc += u;
    }
    if (lane == 63) wsum[w] = inc;
    __syncthreads();
    if (w == 0 && lane < 16) {
        int ws = wsum[lane];
        int winc = ws;
#pragma unroll
        for (int off = 1; off < 16; off <<= 1) {
            int u = __shfl_up(winc, off);
            if (lane >= off) winc += u;
        }
        wsum[lane] = winc - ws;   // exclusive
    }
    __syncthreads();
    int run = wsum[w] + (inc - s);
    int tbase = run;
#pragma unroll
    for (int i = 0; i < 4; ++i) {
        if (base + i < nkeys) bstart[base + i] = run;
        run += v[i];
    }
    if (t == 1023) partial[blockIdx.x] = tbase + s;   // block total
}

__global__ __launch_bounds__(64) void scanB_kernel(
    const int* __restrict__ partial, int* __restrict__ pscan,
    int* __restrict__ bstart_end, int nblk)
{
    const int lane = threadIdx.x;
    int running = 0;
    for (int b = 0; b < nblk; b += 64) {
        int i = b + lane;
        int o = (i < nblk) ? partial[i] : 0;
        int v = o;
#pragma unroll
        for (int off = 1; off < 64; off <<= 1) {
            int u = __shfl_up(v, off);
            if (lane >= off) v += u;
        }
        if (i < nblk) pscan[i] = running + v - o;
        running += __shfl(v, 63);
    }
    if (lane == 0) *bstart_end = running;   // == E
}

__global__ __launch_bounds__(1024) void scanC_kernel(
    int* __restrict__ bstart, const int* __restrict__ pscan, int nkeys)
{
    int i = blockIdx.x * 1024 + threadIdx.x;
    if (i < nkeys) bstart[i] += pscan[i / SCAN_TILE];
}

__global__ __launch_bounds__(256) void scatter8_kernel(
    const int* __restrict__ src, const int* __restrict__ dst,
    const int* __restrict__ et, const int* __restrict__ bstart,
    int* __restrict__ cursor, unsigned* __restrict__ srt, int E)
{
    int e = blockIdx.x * 256 + threadIdx.x;
    if (e < E) {
        int key = dst[e] * 8 + et[e];
        int pos = bstart[key] + atomicAdd(&cursor[key], 1);
        srt[pos] = (unsigned)src[e];
    }
}

// ---------- x -> compact f16 ----------
__global__ __launch_bounds__(256) void xprep_kernel(
    const float* __restrict__ x, unsigned short* __restrict__ xh, int n)
{
    int i = blockIdx.x * 256 + threadIdx.x;
    if (i < n) xh[i] = f2h(x[i]);
}

// ---------- W preconversion: f16 image, chunk c: [j][k stride 72] ----------

__global__ __launch_bounds__(256) void wprep_kernel(
    const float* __restrict__ W, const float* __restrict__ root,
    unsigned short* __restrict__ wb, int dout)
{
    int idx = blockIdx.x * 256 + threadIdx.x;
    int total = 9 * 64 * dout;
    if (idx >= total) return;
    int c = idx / (64 * dout);
    int rme = idx % (64 * dout);
    int kk = rme / dout;
    int j = rme % dout;
    float f = (c == 0) ? root[kk * dout + j]
                       : W[(size_t)(c - 1) * 64 * dout + kk * dout + j];
    wb[(size_t)c * dout * 72 + (size_t)j * 72 + kk] = f2h(f);
}

// ---------- aggregation: one wave per node, lane = feature dim ----------
// Single running accumulator + ordered boundary flush (edges are
// (dst,rel)-sorted; boundaries from bstart). ~7 VALU/edge vs 8-way select.
// Writes A[n] = [ feat[n] | mean_0 .. mean_7 ] (f16, 576 cols).

__global__ __launch_bounds__(512) void agg_kernel(
    const unsigned short* __restrict__ feat,  // (N, 64) f16 compact
    const unsigned* __restrict__ srt,         // sorted src indices
    const int* __restrict__ bstart,           // (N*8 + 1)
    unsigned short* __restrict__ A,           // (N, 576) f16
    int n_nodes)
{
    const int t = threadIdx.x;
    const int lane = t & 63;
    const int node = blockIdx.x * 8 + (t >> 6);
    if (node >= n_nodes) return;

    int myb = (lane < 9) ? bstart[node * 8 + lane] : 0;
    const int e0 = __shfl(myb, 0);
    const int e1 = __shfl(myb, 8);

    unsigned short* arow = A + (size_t)node * 576;
    arow[lane] = feat[(size_t)node * 64 + lane];   // self features

    float p = 0.0f;
    int r = 0;
    int seg_start = e0;
    int next_b = __shfl(myb, 1);

    // flush all segments ending at edge-position g (bounded: r<8)
    auto flush_at = [&](int g) {
        while (r < 8 && g == next_b) {
            const int cnt = next_b - seg_start;
            const float sc = (cnt > 0) ? (1.0f / (float)cnt) : 0.0f;
            arow[64 + (r << 6) + lane] = f2h(p * sc);
            p = 0.0f;
            seg_start = next_b;
            ++r;
            next_b = __shfl(myb, min(r + 1, 8));
        }
    };

#define GATHER(i) h2f(feat[(size_t)__shfl(rec, (i)) * 64 + lane])

    for (int base = e0; base < e1; base += 64) {
        const int blen = min(64, e1 - base);
        unsigned rec = (lane < blen) ? srt[base + lane] : 0u;
        float v0 = 0.f, v1 = 0.f, v2 = 0.f, v3 = 0.f;
        if (0 < blen) v0 = GATHER(0);
        if (1 < blen) v1 = GATHER(1);
        if (2 < blen) v2 = GATHER(2);
        if (3 < blen) v3 = GATHER(3);
        int k = 0;
        for (; k + 4 <= blen; k += 4) {
            float n0 = 0.f, n1 = 0.f, n2 = 0.f, n3 = 0.f;
            if (k + 4 < blen) n0 = GATHER(k + 4);
            if (k + 5 < blen) n1 = GATHER(k + 5);
            if (k + 6 < blen) n2 = GATHER(k + 6);
            if (k + 7 < blen) n3 = GATHER(k + 7);
            flush_at(base + k);     p += v0;
            flush_at(base + k + 1); p += v1;
            flush_at(base + k + 2); p += v2;
            flush_at(base + k + 3); p += v3;
            v0 = n0; v1 = n1; v2 = n2; v3 = n3;
        }
        for (; k < blen; ++k) {
            flush_at(base + k);
            p += v0;
            v0 = v1; v1 = v2; v2 = v3;
        }
    }
#undef GATHER

    // trailing segments (those ending exactly at e1, incl. empty ones)
    while (r < 8) {
        const int cnt = next_b - seg_start;
        const float sc = (cnt > 0) ? (1.0f / (float)cnt) : 0.0f;
        arow[64 + (r << 6) + lane] = f2h(p * sc);
        p = 0.0f;
        seg_start = next_b;
        ++r;
        next_b = __shfl(myb, min(r + 1, 8));
    }
}

// ---------- dense: C = A @ [root; W] + b, f16 MFMA, whole W in LDS ----------
// Block = 128 nodes, 512 threads = 8 waves (wave = one 16-row m-tile, all j).

template <int DOUT, int RELU, int OUTH>
__global__ __launch_bounds__(512, 2) void dense_kernel(
    const unsigned short* __restrict__ A,   // (N, 576) f16
    const unsigned short* __restrict__ wb,  // (9, DOUT, 72) f16
    const float* __restrict__ bias,
    float* __restrict__ outf,               // fp32 out (OUTH=0)
    unsigned short* __restrict__ outh,      // f16 out, compact (N,64) (OUTH=1)
    int n_nodes)
{
    constexpr int WSHORTS = 9 * DOUT * 72;
    __shared__ __align__(16) unsigned short wt_s[WSHORTS];

    const int t = threadIdx.x;
    const int w = t >> 6, lane = t & 63;
    const int quad = lane >> 4, l16 = lane & 15;
    const int node0 = blockIdx.x * 128;
    const int m = w * 16 + l16;
    const int row = min(node0 + m, n_nodes - 1);
    const unsigned short* arow = A + (size_t)row * 576;

    half8 a[18];
#pragma unroll
    for (int c = 0; c < 9; ++c) {
        a[2 * c]     = *(const half8*)(arow + c * 64 + quad * 8);
        a[2 * c + 1] = *(const half8*)(arow + c * 64 + 32 + quad * 8);
    }
    {
        uint4* d4 = (uint4*)wt_s;
        const uint4* s4 = (const uint4*)wb;
        for (int i = t; i < WSHORTS / 8; i += 512) d4[i] = s4[i];
    }
    __syncthreads();

    constexpr int JPW = DOUT / 16;
    f32x4 d[JPW];
#pragma unroll
    for (int i = 0; i < JPW; ++i) d[i] = {0.f, 0.f, 0.f, 0.f};

#pragma unroll
    for (int c = 0; c < 9; ++c) {
#pragma unroll
        for (int jj = 0; jj < JPW; ++jj) {
            const int j = jj * 16 + l16;
            half8 b0 = *(const half8*)&wt_s[c * DOUT * 72 + j * 72 + quad * 8];
            half8 b1 = *(const half8*)&wt_s[c * DOUT * 72 + j * 72 + 32 + quad * 8];
            d[jj] = __builtin_amdgcn_mfma_f32_16x16x32_f16(a[2 * c], b0, d[jj], 0, 0, 0);
            d[jj] = __builtin_amdgcn_mfma_f32_16x16x32_f16(a[2 * c + 1], b1, d[jj], 0, 0, 0);
        }
    }

    // epilogue: C/D layout col = lane&15 (j), row = quad*4 + reg (m)
#pragma unroll
    for (int jj = 0; jj < JPW; ++jj) {
        const int j = jj * 16 + l16;
        const float bj = bias[j];
#pragma unroll
        for (int r = 0; r < 4; ++r) {
            const int node = node0 + w * 16 + quad * 4 + r;
            if (node < n_nodes) {
                float v = d[jj][r] + bj;
                if (RELU) v = fmaxf(v, 0.0f);
                if (OUTH) outh[(size_t)node * 64 + j] = f2h(v);
                else      outf[(size_t)node * DOUT + j] = v;
            }
        }
    }
}

extern "C" void kernel_launch(void* const* d_in, const int* in_sizes, int n_in,
                              void* d_out, int out_size, void* d_ws, size_t ws_size,
                              hipStream_t stream) {
    const float* x     = (const float*)d_in[0];
    const float* W1    = (const float*)d_in[1];
    const float* root1 = (const float*)d_in[2];
    const float* b1    = (const float*)d_in[3];
    const float* W2    = (const float*)d_in[4];
    const float* root2 = (const float*)d_in[5];
    const float* b2    = (const float*)d_in[6];
    const int*   src   = (const int*)d_in[7];
    const int*   dst   = (const int*)d_in[8];
    const int*   et    = (const int*)d_in[9];

    const int N = in_sizes[0] / 64;
    const int E = in_sizes[7];
    const int KEYS = N * 8;

    char* p = (char*)d_ws;
    auto alloc = [&](size_t bytes) {
        char* r = p;
        p += (bytes + 15) & ~(size_t)15;
        return r;
    };
    unsigned* srt       = (unsigned*)alloc((size_t)E * 4);
    int* hist           = (int*)alloc((size_t)KEYS * 4);   // hist|cursor adjacent
    int* cursor         = (int*)alloc((size_t)KEYS * 4);
    int* bstart         = (int*)alloc((size_t)(KEYS + 1) * 4);
    int* partial        = (int*)alloc(256 * 4);
    int* pscan          = (int*)alloc(256 * 4);
    unsigned short* wb1 = (unsigned short*)alloc((size_t)9 * 64 * 72 * 2);
    unsigned short* wb2 = (unsigned short*)alloc((size_t)9 * 32 * 72 * 2);
    unsigned short* xh  = (unsigned short*)alloc((size_t)N * 64 * 2);
    unsigned short* hC  = (unsigned short*)alloc((size_t)N * 64 * 2);
    unsigned short* A   = (unsigned short*)alloc((size_t)N * 576 * 2);
    (void)cursor;  // memset covers hist+cursor together (contiguous)

    hipMemsetAsync(hist, 0, (size_t)KEYS * 8, stream);
    wprep_kernel<<<(9 * 64 * 64 + 255) / 256, 256, 0, stream>>>(W1, root1, wb1, 64);
    wprep_kernel<<<(9 * 64 * 32 + 255) / 256, 256, 0, stream>>>(W2, root2, wb2, 32);
    xprep_kernel<<<(N * 64 + 255) / 256, 256, 0, stream>>>(x, xh, N * 64);
    hist8_kernel<<<(E + 255) / 256, 256, 0, stream>>>(dst, et, hist, E);
    const int nscan = (KEYS + SCAN_TILE - 1) / SCAN_TILE;
    scanA_kernel<<<nscan, 1024, 0, stream>>>(hist, bstart, partial, KEYS);
    scanB_kernel<<<1, 64, 0, stream>>>(partial, pscan, bstart + KEYS, nscan);
    scanC_kernel<<<(KEYS + 1023) / 1024, 1024, 0, stream>>>(bstart, pscan, KEYS);
    scatter8_kernel<<<(E + 255) / 256, 256, 0, stream>>>(src, dst, et, bstart, cursor, srt, E);

    agg_kernel<<<(N + 7) / 8, 512, 0, stream>>>(xh, srt, bstart, A, N);
    dense_kernel<64, 1, 1><<<(N + 127) / 128, 512, 0, stream>>>(
        A, wb1, b1, nullptr, hC, N);
    agg_kernel<<<(N + 7) / 8, 512, 0, stream>>>(hC, srt, bstart, A, N);
    dense_kernel<32, 0, 0><<<(N + 127) / 128, 512, 0, stream>>>(
        A, wb2, b2, (float*)d_out, nullptr, N);
}